// Round 10
// baseline (225.733 us; speedup 1.0000x reference)
//
#include <hip/hip_runtime.h>
#include <hip/hip_bf16.h>
#include <math.h>

typedef __attribute__((ext_vector_type(8))) short bf16x8;
typedef __attribute__((ext_vector_type(16))) float f32x16;

#define B_ 2
#define L_ 2048
#define S_ 2048
#define H_ 16
#define E_ 64
#define D_ 64

#define EXP2(x) exp2f(x)

#define CNT_BYTES 4096
#define SLOT_BYTES 36864ull          // 4 subs x 8KB acc + 2KB ml, padded
#define WS_NEED (CNT_BYTES + 512ull * 2ull * SLOT_BYTES)

__device__ __forceinline__ unsigned pkbf(float a, float b) {
  __hip_bfloat162 hh = __float22bfloat162_rn(float2{a, b});
  return *(unsigned*)&hh;
}

// D-frag row for mfma_f32_32x32x16: row = (r&3) + 8*(r>>2) + 4*hi5
__device__ __forceinline__ int crow(int r, int hi5) {
  return (r & 3) + ((r >> 2) << 3) + (hi5 << 2);
}

__global__ void fa_init(int* cnt) {
  if (threadIdx.x < 512) cnt[threadIdx.x] = 0;
}

template<int NCHUNKS>
__global__ __launch_bounds__(256, 4)
void fa_fwd8(const float* __restrict__ Qp, const float* __restrict__ Kp,
             const float* __restrict__ Vp, float* __restrict__ Op,
             char* __restrict__ ws) {
  // double-buffered: [buf][ K tile (8KB) | V^T tile (8KB) ] = 32KB
  __shared__ uint4 sbuf[2][1024];
  __shared__ int role;

  const int tid  = threadIdx.x;
  const int lane = tid & 63;
  const int sub  = tid >> 6;      // 4 waves = 4 q-subtiles (32 rows each)
  const int l31  = lane & 31;
  const int hi5  = lane >> 5;

  // XCD-chunked mapping, heavy q first; chunk pairs adjacent.
  const int Bx  = blockIdx.x;
  const int xcd = Bx & 7;
  const int i_  = Bx >> 3;
  const int bh  = xcd * 4 + (i_ & 3);
  const int rest = i_ >> 2;
  const int qidx  = (NCHUNKS == 2) ? (15 - (rest >> 1)) : (15 - rest);
  const int chunk = (NCHUNKS == 2) ? (rest & 1) : 0;
  const int b   = bh >> 4, h = bh & 15;
  const int q0  = qidx << 7;          // 128-row q block
  const int qw  = q0 + sub * 32;      // this wave's 32 q-rows
  const int R   = (NCHUNKS == 2) ? (qidx + 1) : (2 * qidx + 2); // tiles in my chunk
  const int t0  = chunk * (qidx + 1);

  const float cs = 0.125f * 1.44269504088896f;  // 1/sqrt(E) * log2(e)

  // staging coords
  const int krow = tid >> 2, ksg = tid & 3;     // K: 64 rows x 4 segs
  const int vd   = tid & 63, kg  = tid >> 6;    // V: 64 d-cols x 4 kv-groups
  const int kswz = (krow & 7) << 4;
  const int vswz = (vd & 7) << 4;

  // ---- Q fragments (B-operand of swapped QK^T), pre-scaled, in regs ----
  bf16x8 qf[4];
  {
    const int qg = qw + l31;
    const float* gq = Qp + ((size_t)(b * L_ + qg) * H_ + h) * E_ + hi5 * 8;
    #pragma unroll
    for (int ec = 0; ec < 4; ++ec) {
      float4 a = *(const float4*)(gq + ec * 16);
      float4 c = *(const float4*)(gq + ec * 16 + 4);
      uint4 u;
      u.x = pkbf(a.x * cs, a.y * cs);
      u.y = pkbf(a.z * cs, a.w * cs);
      u.z = pkbf(c.x * cs, c.y * cs);
      u.w = pkbf(c.z * cs, c.w * cs);
      qf[ec] = *(bf16x8*)&u;
    }
  }

  f32x16 acc[2];
  #pragma unroll
  for (int dt = 0; dt < 2; ++dt)
    #pragma unroll
    for (int rr = 0; rr < 16; ++rr) acc[dt][rr] = 0.f;

  float mrun = -INFINITY;
  float lsum = 0.f;

  // ---- prologue: stage tile t0 into buf 0 ----
  {
    char* lk = (char*)&sbuf[0][0];
    char* lv = lk + 8192;
    const int kv0 = t0 * 64;
    const float* gk = Kp + ((size_t)(b * S_ + kv0 + krow) * H_ + h) * E_ + ksg * 8;
    #pragma unroll
    for (int j = 0; j < 2; ++j) {
      float4 a = *(const float4*)(gk + j * 32);
      float4 c = *(const float4*)(gk + j * 32 + 4);
      uint4 u;
      u.x = pkbf(a.x, a.y); u.y = pkbf(a.z, a.w);
      u.z = pkbf(c.x, c.y); u.w = pkbf(c.z, c.w);
      *(uint4*)(lk + ((krow * 128 + ksg * 16 + j * 64) ^ kswz)) = u;
    }
    #pragma unroll
    for (int j = 0; j < 2; ++j) {
      const float* gv = Vp + ((size_t)(b * S_ + kv0 + kg * 16 + j * 8) * H_ + h) * D_ + vd;
      float v0 = gv[(size_t)0 * (H_ * D_)];
      float v1 = gv[(size_t)1 * (H_ * D_)];
      float v2 = gv[(size_t)2 * (H_ * D_)];
      float v3 = gv[(size_t)3 * (H_ * D_)];
      float v4 = gv[(size_t)4 * (H_ * D_)];
      float v5 = gv[(size_t)5 * (H_ * D_)];
      float v6 = gv[(size_t)6 * (H_ * D_)];
      float v7 = gv[(size_t)7 * (H_ * D_)];
      uint4 u;
      u.x = pkbf(v0, v1); u.y = pkbf(v2, v3);
      u.z = pkbf(v4, v5); u.w = pkbf(v6, v7);
      *(uint4*)(lv + ((vd * 128 + kg * 32 + j * 16) ^ vswz)) = u;
    }
  }
  __syncthreads();

  int cur = 0;
  for (int t = t0; t < t0 + R; ++t, cur ^= 1) {
    const int kv0 = t * 64;
    const bool have_next = (t + 1) < (t0 + R);

    // ---- issue next-tile global loads EARLY ----
    float4 Ka[2], Kc[2];
    float Vv[16];
    if (have_next) {
      const int kvn = kv0 + 64;
      const float* gk = Kp + ((size_t)(b * S_ + kvn + krow) * H_ + h) * E_ + ksg * 8;
      Ka[0] = *(const float4*)(gk);
      Kc[0] = *(const float4*)(gk + 4);
      Ka[1] = *(const float4*)(gk + 32);
      Kc[1] = *(const float4*)(gk + 36);
      #pragma unroll
      for (int j = 0; j < 2; ++j) {
        const float* gv = Vp + ((size_t)(b * S_ + kvn + kg * 16 + j * 8) * H_ + h) * D_ + vd;
        #pragma unroll
        for (int k2 = 0; k2 < 8; ++k2)
          Vv[j * 8 + k2] = gv[(size_t)k2 * (H_ * D_)];
      }
    }

    // ---- compute on buf[cur] (masked waves skip; barriers stay matched) ----
    if (kv0 <= qw + 31) {
      char* lk = (char*)&sbuf[cur][0];
      char* lv = lk + 8192;
      const bool needmask = (kv0 + 63) > qw;

      f32x16 st[2];
      #pragma unroll
      for (int c = 0; c < 2; ++c)
        #pragma unroll
        for (int rr = 0; rr < 16; ++rr) st[c][rr] = 0.f;
      __builtin_amdgcn_s_setprio(1);
      #pragma unroll
      for (int c = 0; c < 2; ++c) {
        const int row = c * 32 + l31;
        const int sw = (row & 7) << 4;
        #pragma unroll
        for (int ec = 0; ec < 4; ++ec) {
          bf16x8 kf = *(bf16x8*)(lk + ((row * 128 + ec * 32 + hi5 * 16) ^ sw));
          st[c] = __builtin_amdgcn_mfma_f32_32x32x16_bf16(kf, qf[ec], st[c], 0, 0, 0);
        }
      }
      __builtin_amdgcn_s_setprio(0);

      if (needmask) {
        const int qg = qw + l31;
        #pragma unroll
        for (int c = 0; c < 2; ++c)
          #pragma unroll
          for (int rr = 0; rr < 16; ++rr)
            if (kv0 + c * 32 + crow(rr, hi5) > qg) st[c][rr] = -1e30f;
      }

      // online softmax, defer-max (THR=8 in log2 domain)
      float pm = st[0][0];
      #pragma unroll
      for (int c = 0; c < 2; ++c)
        #pragma unroll
        for (int rr = 0; rr < 16; ++rr) pm = fmaxf(pm, st[c][rr]);
      pm = fmaxf(pm, __shfl_xor(pm, 32));

      if (__any(pm > mrun + 8.f)) {
        const float mn = fmaxf(mrun, pm);
        const float f = EXP2(mrun - mn);
        mrun = mn;
        lsum *= f;
        #pragma unroll
        for (int rr = 0; rr < 16; ++rr) {
          const float fr = __shfl(f, crow(rr, hi5));
          acc[0][rr] *= fr;
          acc[1][rr] *= fr;
        }
      }
      {
        float ps = 0.f;
        #pragma unroll
        for (int c = 0; c < 2; ++c)
          #pragma unroll
          for (int rr = 0; rr < 16; ++rr) {
            st[c][rr] = EXP2(st[c][rr] - mrun);
            ps += st[c][rr];
          }
        ps += __shfl_xor(ps, 32);
        lsum += ps;
      }

      // P -> PA fragments (pack pairs + lane^32 exchange)
      uint4 pa[4];
      #pragma unroll
      for (int c = 0; c < 2; ++c) {
        unsigned Dw[8];
        #pragma unroll
        for (int j = 0; j < 8; ++j)
          Dw[j] = pkbf(st[c][2 * j], st[c][2 * j + 1]);
        unsigned y0 = __shfl_xor((int)(hi5 ? Dw[0] : Dw[2]), 32);
        unsigned y1 = __shfl_xor((int)(hi5 ? Dw[1] : Dw[3]), 32);
        unsigned y2 = __shfl_xor((int)(hi5 ? Dw[4] : Dw[6]), 32);
        unsigned y3 = __shfl_xor((int)(hi5 ? Dw[5] : Dw[7]), 32);
        uint4 p0, p1;
        if (hi5) {
          p0 = uint4{y0, y1, Dw[2], Dw[3]};
          p1 = uint4{y2, y3, Dw[6], Dw[7]};
        } else {
          p0 = uint4{Dw[0], Dw[1], y0, y1};
          p1 = uint4{Dw[4], Dw[5], y2, y3};
        }
        pa[2 * c]     = p0;
        pa[2 * c + 1] = p1;
      }

      // PV: acc[dt] += P(32q x 16kv) . V(16kv x 32d)
      __builtin_amdgcn_s_setprio(1);
      #pragma unroll
      for (int s = 0; s < 4; ++s) {
        #pragma unroll
        for (int dt = 0; dt < 2; ++dt) {
          const int row = dt * 32 + l31;
          bf16x8 vf = *(bf16x8*)(lv + ((row * 128 + s * 32 + hi5 * 16) ^ ((row & 7) << 4)));
          acc[dt] = __builtin_amdgcn_mfma_f32_32x32x16_bf16(*(bf16x8*)&pa[s], vf, acc[dt], 0, 0, 0);
        }
      }
      __builtin_amdgcn_s_setprio(0);
    }

    // ---- write next tile into the other buffer ----
    if (have_next) {
      char* lk = (char*)&sbuf[cur ^ 1][0];
      char* lv = lk + 8192;
      #pragma unroll
      for (int j = 0; j < 2; ++j) {
        uint4 u;
        u.x = pkbf(Ka[j].x, Ka[j].y); u.y = pkbf(Ka[j].z, Ka[j].w);
        u.z = pkbf(Kc[j].x, Kc[j].y); u.w = pkbf(Kc[j].z, Kc[j].w);
        *(uint4*)(lk + ((krow * 128 + ksg * 16 + j * 64) ^ kswz)) = u;
      }
      #pragma unroll
      for (int j = 0; j < 2; ++j) {
        uint4 u;
        u.x = pkbf(Vv[j * 8 + 0], Vv[j * 8 + 1]);
        u.y = pkbf(Vv[j * 8 + 2], Vv[j * 8 + 3]);
        u.z = pkbf(Vv[j * 8 + 4], Vv[j * 8 + 5]);
        u.w = pkbf(Vv[j * 8 + 6], Vv[j * 8 + 7]);
        *(uint4*)(lv + ((vd * 128 + kg * 32 + j * 16) ^ vswz)) = u;
      }
    }
    __syncthreads();
  }

  if (NCHUNKS == 1) {
    // ---- direct epilogue: O[q][d] = acc / lsum ----
    const float inv = 1.f / lsum;
    #pragma unroll
    for (int rr = 0; rr < 16; ++rr) {
      const float wr = __shfl(inv, crow(rr, hi5));
      const int qg = qw + crow(rr, hi5);
      float* go = Op + ((size_t)(b * L_ + qg) * H_ + h) * D_ + l31;
      go[0]  = acc[0][rr] * wr;
      go[32] = acc[1][rr] * wr;
    }
    return;
  }

  // ---- split-KV: write partial, second arriver merges ----
  const int g = bh * 16 + qidx;
  int* cnt = (int*)ws;
  char* slotme = ws + CNT_BYTES + ((size_t)(g * 2 + chunk)) * SLOT_BYTES;
  char* slotpk = ws + CNT_BYTES + ((size_t)(g * 2 + (chunk ^ 1))) * SLOT_BYTES;

  {
    float4* pw = (float4*)(slotme + sub * 8192);
    #pragma unroll
    for (int dt = 0; dt < 2; ++dt)
      #pragma unroll
      for (int j = 0; j < 4; ++j)
        pw[(dt * 4 + j) * 64 + lane] = ((float4*)&acc[dt])[j];
    ((float2*)(slotme + 32768))[sub * 64 + lane] = float2{mrun, lsum};
  }
  __syncthreads();
  if (tid == 0) {
    __builtin_amdgcn_fence(__ATOMIC_RELEASE, "agent");
    role = atomicAdd(&cnt[g], 1);
  }
  __syncthreads();
  if (role != 1) return;   // first arriver: partner will merge

  __builtin_amdgcn_fence(__ATOMIC_ACQUIRE, "agent");
  f32x16 p0, p1;
  {
    float4* pr = (float4*)(slotpk + sub * 8192);
    #pragma unroll
    for (int j = 0; j < 4; ++j) {
      ((float4*)&p0)[j] = pr[(0 * 4 + j) * 64 + lane];
      ((float4*)&p1)[j] = pr[(1 * 4 + j) * 64 + lane];
    }
  }
  float2 ml1 = ((float2*)(slotpk + 32768))[sub * 64 + lane];
  const float m1 = ml1.x, l1 = ml1.y;
  const float mm = fmaxf(mrun, m1);
  const float f0 = EXP2(mrun - mm);
  const float f1 = EXP2(m1 - mm);    // exp2(-inf)=0 covers empty partials
  const float inv = 1.f / (lsum * f0 + l1 * f1);
  const float g0 = f0 * inv, g1 = f1 * inv;
  #pragma unroll
  for (int rr = 0; rr < 16; ++rr) {
    const int cr = crow(rr, hi5);
    const float w0 = __shfl(g0, cr);
    const float w1 = __shfl(g1, cr);
    const int qg = qw + cr;
    float* go = Op + ((size_t)(b * L_ + qg) * H_ + h) * D_ + l31;
    go[0]  = acc[0][rr] * w0 + p0[rr] * w1;
    go[32] = acc[1][rr] * w0 + p1[rr] * w1;
  }
}

extern "C" void kernel_launch(void* const* d_in, const int* in_sizes, int n_in,
                              void* d_out, int out_size, void* d_ws, size_t ws_size,
                              hipStream_t stream) {
  (void)in_sizes; (void)n_in; (void)out_size;
  const float* Q = (const float*)d_in[0];
  const float* K = (const float*)d_in[1];
  const float* V = (const float*)d_in[2];
  float* O = (float*)d_out;
  if (ws_size >= WS_NEED) {
    fa_init<<<dim3(1), dim3(512), 0, stream>>>((int*)d_ws);
    fa_fwd8<2><<<dim3(1024), dim3(256), 0, stream>>>(Q, K, V, O, (char*)d_ws);
  } else {
    fa_fwd8<1><<<dim3(512), dim3(256), 0, stream>>>(Q, K, V, O, (char*)d_ws);
  }
}

// Round 11
// 100.292 us; speedup vs baseline: 2.2508x; 2.2508x over previous
//
#include <hip/hip_runtime.h>
#include <hip/hip_bf16.h>
#include <math.h>

typedef __attribute__((ext_vector_type(8))) short bf16x8;
typedef __attribute__((ext_vector_type(16))) float f32x16;

#define B_ 2
#define L_ 2048
#define S_ 2048
#define H_ 16
#define E_ 64
#define D_ 64

#define EXP2(x) exp2f(x)

#define CNT_BYTES 4096
#define SLOT_BYTES 36864ull          // 4 subs x 8KB acc + 2KB ml, padded
#define WS_NEED (CNT_BYTES + 512ull * 2ull * SLOT_BYTES)

__device__ __forceinline__ unsigned pkbf(float a, float b) {
  __hip_bfloat162 hh = __float22bfloat162_rn(float2{a, b});
  return *(unsigned*)&hh;
}

// D-frag row for mfma_f32_32x32x16: row = (r&3) + 8*(r>>2) + 4*hi5
__device__ __forceinline__ int crow(int r, int hi5) {
  return (r & 3) + ((r >> 2) << 3) + (hi5 << 2);
}

__global__ void fa_init(int* cnt) {
  if (threadIdx.x < 512) cnt[threadIdx.x] = 0;
}

// launch_bounds(256,3): VGPR cap ~170 total (arch+acc). This kernel's peak
// live state is ~144 (80 arch + 64 acc) -> fits with NO SPILL, 3 waves/SIMD.
// (256,4) capped at 128 and spilled every K-iteration -> 270MB FETCH (r10).
template<int NCHUNKS>
__global__ __launch_bounds__(256, 3)
void fa_fwd9(const float* __restrict__ Qp, const float* __restrict__ Kp,
             const float* __restrict__ Vp, float* __restrict__ Op,
             char* __restrict__ ws) {
  // double-buffered: [buf][ K tile (8KB) | V^T tile (8KB) ] = 32KB
  __shared__ uint4 sbuf[2][1024];
  __shared__ int role;

  const int tid  = threadIdx.x;
  const int lane = tid & 63;
  const int sub  = tid >> 6;      // 4 waves = 4 q-subtiles (32 rows each)
  const int l31  = lane & 31;
  const int hi5  = lane >> 5;

  // XCD-chunked mapping, heavy q first; chunk pairs adjacent.
  const int Bx  = blockIdx.x;
  const int xcd = Bx & 7;
  const int i_  = Bx >> 3;
  const int bh  = xcd * 4 + (i_ & 3);
  const int rest = i_ >> 2;
  const int qidx  = (NCHUNKS == 2) ? (15 - (rest >> 1)) : (15 - rest);
  const int chunk = (NCHUNKS == 2) ? (rest & 1) : 0;
  const int b   = bh >> 4, h = bh & 15;
  const int q0  = qidx << 7;          // 128-row q block
  const int qw  = q0 + sub * 32;      // this wave's 32 q-rows
  const int R   = (NCHUNKS == 2) ? (qidx + 1) : (2 * qidx + 2); // tiles in my chunk
  const int t0  = chunk * (qidx + 1);

  const float cs = 0.125f * 1.44269504088896f;  // 1/sqrt(E) * log2(e)

  // staging coords
  const int krow = tid >> 2, ksg = tid & 3;     // K: 64 rows x 4 segs
  const int vd   = tid & 63, kg  = tid >> 6;    // V: 64 d-cols x 4 kv-groups
  const int kswz = (krow & 7) << 4;
  const int vswz = (vd & 7) << 4;

  // ---- Q fragments (B-operand of swapped QK^T), pre-scaled, in regs ----
  bf16x8 qf[4];
  {
    const int qg = qw + l31;
    const float* gq = Qp + ((size_t)(b * L_ + qg) * H_ + h) * E_ + hi5 * 8;
    #pragma unroll
    for (int ec = 0; ec < 4; ++ec) {
      float4 a = *(const float4*)(gq + ec * 16);
      float4 c = *(const float4*)(gq + ec * 16 + 4);
      uint4 u;
      u.x = pkbf(a.x * cs, a.y * cs);
      u.y = pkbf(a.z * cs, a.w * cs);
      u.z = pkbf(c.x * cs, c.y * cs);
      u.w = pkbf(c.z * cs, c.w * cs);
      qf[ec] = *(bf16x8*)&u;
    }
  }

  f32x16 acc[2];
  #pragma unroll
  for (int dt = 0; dt < 2; ++dt)
    #pragma unroll
    for (int rr = 0; rr < 16; ++rr) acc[dt][rr] = 0.f;

  float mrun = -INFINITY;
  float lsum = 0.f;

  // ---- prologue: stage tile t0 into buf 0 ----
  {
    char* lk = (char*)&sbuf[0][0];
    char* lv = lk + 8192;
    const int kv0 = t0 * 64;
    const float* gk = Kp + ((size_t)(b * S_ + kv0 + krow) * H_ + h) * E_ + ksg * 8;
    #pragma unroll
    for (int j = 0; j < 2; ++j) {
      float4 a = *(const float4*)(gk + j * 32);
      float4 c = *(const float4*)(gk + j * 32 + 4);
      uint4 u;
      u.x = pkbf(a.x, a.y); u.y = pkbf(a.z, a.w);
      u.z = pkbf(c.x, c.y); u.w = pkbf(c.z, c.w);
      *(uint4*)(lk + ((krow * 128 + ksg * 16 + j * 64) ^ kswz)) = u;
    }
    #pragma unroll
    for (int j = 0; j < 2; ++j) {
      const float* gv = Vp + ((size_t)(b * S_ + kv0 + kg * 16 + j * 8) * H_ + h) * D_ + vd;
      float v0 = gv[(size_t)0 * (H_ * D_)];
      float v1 = gv[(size_t)1 * (H_ * D_)];
      float v2 = gv[(size_t)2 * (H_ * D_)];
      float v3 = gv[(size_t)3 * (H_ * D_)];
      float v4 = gv[(size_t)4 * (H_ * D_)];
      float v5 = gv[(size_t)5 * (H_ * D_)];
      float v6 = gv[(size_t)6 * (H_ * D_)];
      float v7 = gv[(size_t)7 * (H_ * D_)];
      uint4 u;
      u.x = pkbf(v0, v1); u.y = pkbf(v2, v3);
      u.z = pkbf(v4, v5); u.w = pkbf(v6, v7);
      *(uint4*)(lv + ((vd * 128 + kg * 32 + j * 16) ^ vswz)) = u;
    }
  }
  __syncthreads();

  int cur = 0;
  for (int t = t0; t < t0 + R; ++t, cur ^= 1) {
    const int kv0 = t * 64;
    const bool have_next = (t + 1) < (t0 + R);

    // ---- issue next-tile global loads EARLY ----
    float4 Ka[2], Kc[2];
    float Vv[16];
    if (have_next) {
      const int kvn = kv0 + 64;
      const float* gk = Kp + ((size_t)(b * S_ + kvn + krow) * H_ + h) * E_ + ksg * 8;
      Ka[0] = *(const float4*)(gk);
      Kc[0] = *(const float4*)(gk + 4);
      Ka[1] = *(const float4*)(gk + 32);
      Kc[1] = *(const float4*)(gk + 36);
      #pragma unroll
      for (int j = 0; j < 2; ++j) {
        const float* gv = Vp + ((size_t)(b * S_ + kvn + kg * 16 + j * 8) * H_ + h) * D_ + vd;
        #pragma unroll
        for (int k2 = 0; k2 < 8; ++k2)
          Vv[j * 8 + k2] = gv[(size_t)k2 * (H_ * D_)];
      }
    }

    // ---- compute on buf[cur] (masked waves skip; barriers stay matched) ----
    if (kv0 <= qw + 31) {
      char* lk = (char*)&sbuf[cur][0];
      char* lv = lk + 8192;
      const bool needmask = (kv0 + 63) > qw;

      f32x16 st[2];
      #pragma unroll
      for (int c = 0; c < 2; ++c)
        #pragma unroll
        for (int rr = 0; rr < 16; ++rr) st[c][rr] = 0.f;
      __builtin_amdgcn_s_setprio(1);
      #pragma unroll
      for (int c = 0; c < 2; ++c) {
        const int row = c * 32 + l31;
        const int sw = (row & 7) << 4;
        #pragma unroll
        for (int ec = 0; ec < 4; ++ec) {
          bf16x8 kf = *(bf16x8*)(lk + ((row * 128 + ec * 32 + hi5 * 16) ^ sw));
          st[c] = __builtin_amdgcn_mfma_f32_32x32x16_bf16(kf, qf[ec], st[c], 0, 0, 0);
        }
      }
      __builtin_amdgcn_s_setprio(0);

      if (needmask) {
        const int qg = qw + l31;
        #pragma unroll
        for (int c = 0; c < 2; ++c)
          #pragma unroll
          for (int rr = 0; rr < 16; ++rr)
            if (kv0 + c * 32 + crow(rr, hi5) > qg) st[c][rr] = -1e30f;
      }

      // online softmax, defer-max (THR=8 in log2 domain)
      float pm = st[0][0];
      #pragma unroll
      for (int c = 0; c < 2; ++c)
        #pragma unroll
        for (int rr = 0; rr < 16; ++rr) pm = fmaxf(pm, st[c][rr]);
      pm = fmaxf(pm, __shfl_xor(pm, 32));

      if (__any(pm > mrun + 8.f)) {
        const float mn = fmaxf(mrun, pm);
        const float f = EXP2(mrun - mn);
        mrun = mn;
        lsum *= f;
        #pragma unroll
        for (int rr = 0; rr < 16; ++rr) {
          const float fr = __shfl(f, crow(rr, hi5));
          acc[0][rr] *= fr;
          acc[1][rr] *= fr;
        }
      }
      {
        float ps = 0.f;
        #pragma unroll
        for (int c = 0; c < 2; ++c)
          #pragma unroll
          for (int rr = 0; rr < 16; ++rr) {
            st[c][rr] = EXP2(st[c][rr] - mrun);
            ps += st[c][rr];
          }
        ps += __shfl_xor(ps, 32);
        lsum += ps;
      }

      // P -> PA fragments (pack pairs + lane^32 exchange)
      uint4 pa[4];
      #pragma unroll
      for (int c = 0; c < 2; ++c) {
        unsigned Dw[8];
        #pragma unroll
        for (int j = 0; j < 8; ++j)
          Dw[j] = pkbf(st[c][2 * j], st[c][2 * j + 1]);
        unsigned y0 = __shfl_xor((int)(hi5 ? Dw[0] : Dw[2]), 32);
        unsigned y1 = __shfl_xor((int)(hi5 ? Dw[1] : Dw[3]), 32);
        unsigned y2 = __shfl_xor((int)(hi5 ? Dw[4] : Dw[6]), 32);
        unsigned y3 = __shfl_xor((int)(hi5 ? Dw[5] : Dw[7]), 32);
        uint4 p0, p1;
        if (hi5) {
          p0 = uint4{y0, y1, Dw[2], Dw[3]};
          p1 = uint4{y2, y3, Dw[6], Dw[7]};
        } else {
          p0 = uint4{Dw[0], Dw[1], y0, y1};
          p1 = uint4{Dw[4], Dw[5], y2, y3};
        }
        pa[2 * c]     = p0;
        pa[2 * c + 1] = p1;
      }

      // PV: acc[dt] += P(32q x 16kv) . V(16kv x 32d)
      __builtin_amdgcn_s_setprio(1);
      #pragma unroll
      for (int s = 0; s < 4; ++s) {
        #pragma unroll
        for (int dt = 0; dt < 2; ++dt) {
          const int row = dt * 32 + l31;
          bf16x8 vf = *(bf16x8*)(lv + ((row * 128 + s * 32 + hi5 * 16) ^ ((row & 7) << 4)));
          acc[dt] = __builtin_amdgcn_mfma_f32_32x32x16_bf16(*(bf16x8*)&pa[s], vf, acc[dt], 0, 0, 0);
        }
      }
      __builtin_amdgcn_s_setprio(0);
    }

    // ---- write next tile into the other buffer ----
    if (have_next) {
      char* lk = (char*)&sbuf[cur ^ 1][0];
      char* lv = lk + 8192;
      #pragma unroll
      for (int j = 0; j < 2; ++j) {
        uint4 u;
        u.x = pkbf(Ka[j].x, Ka[j].y); u.y = pkbf(Ka[j].z, Ka[j].w);
        u.z = pkbf(Kc[j].x, Kc[j].y); u.w = pkbf(Kc[j].z, Kc[j].w);
        *(uint4*)(lk + ((krow * 128 + ksg * 16 + j * 64) ^ kswz)) = u;
      }
      #pragma unroll
      for (int j = 0; j < 2; ++j) {
        uint4 u;
        u.x = pkbf(Vv[j * 8 + 0], Vv[j * 8 + 1]);
        u.y = pkbf(Vv[j * 8 + 2], Vv[j * 8 + 3]);
        u.z = pkbf(Vv[j * 8 + 4], Vv[j * 8 + 5]);
        u.w = pkbf(Vv[j * 8 + 6], Vv[j * 8 + 7]);
        *(uint4*)(lv + ((vd * 128 + kg * 32 + j * 16) ^ vswz)) = u;
      }
    }
    __syncthreads();
  }

  if (NCHUNKS == 1) {
    // ---- direct epilogue: O[q][d] = acc / lsum ----
    const float inv = 1.f / lsum;
    #pragma unroll
    for (int rr = 0; rr < 16; ++rr) {
      const float wr = __shfl(inv, crow(rr, hi5));
      const int qg = qw + crow(rr, hi5);
      float* go = Op + ((size_t)(b * L_ + qg) * H_ + h) * D_ + l31;
      go[0]  = acc[0][rr] * wr;
      go[32] = acc[1][rr] * wr;
    }
    return;
  }

  // ---- split-KV: write partial, second arriver merges ----
  const int g = bh * 16 + qidx;
  int* cnt = (int*)ws;
  char* slotme = ws + CNT_BYTES + ((size_t)(g * 2 + chunk)) * SLOT_BYTES;
  char* slotpk = ws + CNT_BYTES + ((size_t)(g * 2 + (chunk ^ 1))) * SLOT_BYTES;

  {
    float4* pw = (float4*)(slotme + sub * 8192);
    #pragma unroll
    for (int dt = 0; dt < 2; ++dt)
      #pragma unroll
      for (int j = 0; j < 4; ++j)
        pw[(dt * 4 + j) * 64 + lane] = ((float4*)&acc[dt])[j];
    ((float2*)(slotme + 32768))[sub * 64 + lane] = float2{mrun, lsum};
  }
  __syncthreads();
  if (tid == 0) {
    __builtin_amdgcn_fence(__ATOMIC_RELEASE, "agent");
    role = atomicAdd(&cnt[g], 1);
  }
  __syncthreads();
  if (role != 1) return;   // first arriver: partner will merge

  __builtin_amdgcn_fence(__ATOMIC_ACQUIRE, "agent");
  f32x16 p0, p1;
  {
    float4* pr = (float4*)(slotpk + sub * 8192);
    #pragma unroll
    for (int j = 0; j < 4; ++j) {
      ((float4*)&p0)[j] = pr[(0 * 4 + j) * 64 + lane];
      ((float4*)&p1)[j] = pr[(1 * 4 + j) * 64 + lane];
    }
  }
  float2 ml1 = ((float2*)(slotpk + 32768))[sub * 64 + lane];
  const float m1 = ml1.x, l1 = ml1.y;
  const float mm = fmaxf(mrun, m1);
  const float f0 = EXP2(mrun - mm);
  const float f1 = EXP2(m1 - mm);    // exp2(-inf)=0 covers empty partials
  const float inv = 1.f / (lsum * f0 + l1 * f1);
  const float g0 = f0 * inv, g1 = f1 * inv;
  #pragma unroll
  for (int rr = 0; rr < 16; ++rr) {
    const int cr = crow(rr, hi5);
    const float w0 = __shfl(g0, cr);
    const float w1 = __shfl(g1, cr);
    const int qg = qw + cr;
    float* go = Op + ((size_t)(b * L_ + qg) * H_ + h) * D_ + l31;
    go[0]  = acc[0][rr] * w0 + p0[rr] * w1;
    go[32] = acc[1][rr] * w0 + p1[rr] * w1;
  }
}

extern "C" void kernel_launch(void* const* d_in, const int* in_sizes, int n_in,
                              void* d_out, int out_size, void* d_ws, size_t ws_size,
                              hipStream_t stream) {
  (void)in_sizes; (void)n_in; (void)out_size;
  const float* Q = (const float*)d_in[0];
  const float* K = (const float*)d_in[1];
  const float* V = (const float*)d_in[2];
  float* O = (float*)d_out;
  if (ws_size >= WS_NEED) {
    fa_init<<<dim3(1), dim3(512), 0, stream>>>((int*)d_ws);
    fa_fwd9<2><<<dim3(1024), dim3(256), 0, stream>>>(Q, K, V, O, (char*)d_ws);
  } else {
    fa_fwd9<1><<<dim3(512), dim3(256), 0, stream>>>(Q, K, V, O, (char*)d_ws);
  }
}

// Round 12
// 63.831 us; speedup vs baseline: 3.5364x; 1.5712x over previous
//
#include <hip/hip_runtime.h>
#include <hip/hip_bf16.h>
#include <math.h>

typedef __attribute__((ext_vector_type(8))) short bf16x8;
typedef __attribute__((ext_vector_type(16))) float f32x16;

#define B_ 2
#define L_ 2048
#define S_ 2048
#define H_ 16
#define E_ 64
#define D_ 64
#define EXP2(x) exp2f(x)

// workspace layout: K bf16 images | V^T bf16 images | partials
#define KOFF 0ull
#define VOFF (8ull << 20)
#define POFF (16ull << 20)
#define SLOT_BYTES 18432ull      // 16KB bf16 acc + 2KB (m,l)
#define NSLOTS 1120ull
#define WS_NEED (POFF + NSLOTS * SLOT_BYTES)   // 37.42 MB (<= 37.75 proven, r10)

// global_load_lds: LDS dest = wave-uniform base + lane*16 (lane0's ptr)
#define GLL(gp, lp) __builtin_amdgcn_global_load_lds( \
    (const __attribute__((address_space(1))) unsigned int*)(gp), \
    (__attribute__((address_space(3))) unsigned int*)(lp), 16, 0, 0)

__device__ __forceinline__ unsigned pkbf(float a, float b) {
  __hip_bfloat162 hh = __float22bfloat162_rn(float2{a, b});
  return *(unsigned*)&hh;
}
__device__ __forceinline__ float bf2f(unsigned us) {   // low 16 bits = bf16
  return __uint_as_float(us << 16);
}
// D-frag row for mfma_f32_32x32x16: row = (r&3) + 8*(r>>2) + 4*hi5
__device__ __forceinline__ int crow(int r, int hi5) {
  return (r & 3) + ((r >> 2) << 3) + (hi5 << 2);
}
// KV-chunking schedule: q<3 ->1 chunk, 3<=q<10 ->2, q>=10 ->3 (R<=11)
__device__ __forceinline__ int nchunks(int q) { return (q >= 10) ? 3 : ((q >= 3) ? 2 : 1); }
__device__ __forceinline__ int slotoff(int q, int c) {
  return (q < 3) ? q : (q < 10) ? 3 + (q - 3) * 2 + c : 17 + (q - 10) * 3 + c;
}

// ---------------- pre-pass: bake bf16 swizzled K and V^T tile images --------
__global__ __launch_bounds__(256)
void fa_pre(const float* __restrict__ Kp, const float* __restrict__ Vp,
            char* __restrict__ ws) {
  const int Bx = blockIdx.x;              // 1024 = 32 bh x 32 tiles
  const int bh = Bx & 31, t = Bx >> 5;
  const int b = bh >> 4, h = bh & 15;
  const int kv0 = t * 64;
  const int tid = threadIdx.x;
  char* dk = ws + KOFF + ((size_t)(bh * 32 + t)) * 8192;
  char* dv = ws + VOFF + ((size_t)(bh * 32 + t)) * 8192;
  // K: row = tid>>2 (64 rows), seg = tid&3 (16 e each)
  const int krow = tid >> 2, ksg = tid & 3;
  const int kswz = (krow & 7) << 4;
  const float* gk = Kp + ((size_t)(b * S_ + kv0 + krow) * H_ + h) * E_ + ksg * 16;
  float4 a0 = ((const float4*)gk)[0], a1 = ((const float4*)gk)[1];
  float4 a2 = ((const float4*)gk)[2], a3 = ((const float4*)gk)[3];
  uint4 u0{pkbf(a0.x, a0.y), pkbf(a0.z, a0.w), pkbf(a1.x, a1.y), pkbf(a1.z, a1.w)};
  uint4 u1{pkbf(a2.x, a2.y), pkbf(a2.z, a2.w), pkbf(a3.x, a3.y), pkbf(a3.z, a3.w)};
  *(uint4*)(dk + ((krow * 128 + ksg * 32) ^ kswz)) = u0;
  *(uint4*)(dk + ((krow * 128 + ksg * 32 + 16) ^ kswz)) = u1;
  // V^T: row d = tid&63, kg = tid>>6 (16 kv each), coalesced global reads
  const int vd = tid & 63, kg = tid >> 6;
  const int vswz = (vd & 7) << 4;
  const float* gv = Vp + ((size_t)(b * S_ + kv0 + kg * 16) * H_ + h) * D_ + vd;
  float v[16];
  #pragma unroll
  for (int k = 0; k < 16; ++k) v[k] = gv[(size_t)k * (H_ * D_)];
  uint4 w0{pkbf(v[0], v[1]), pkbf(v[2], v[3]), pkbf(v[4], v[5]), pkbf(v[6], v[7])};
  uint4 w1{pkbf(v[8], v[9]), pkbf(v[10], v[11]), pkbf(v[12], v[13]), pkbf(v[14], v[15])};
  *(uint4*)(dv + ((vd * 128 + kg * 32) ^ vswz)) = w0;
  *(uint4*)(dv + ((vd * 128 + kg * 32 + 16) ^ vswz)) = w1;
}

// ---------------- main: flash loop, gload_lds staging, bf16 partials --------
__global__ __launch_bounds__(256, 3)
void fa_main(const float* __restrict__ Qp, char* __restrict__ ws) {
  __shared__ uint4 sbuf[2][1024];   // [buf] = K image 8KB | V^T image 8KB

  const int tid  = threadIdx.x;
  const int lane = tid & 63;
  const int sub  = tid >> 6;        // 4 waves = 4 q-subtiles (32 rows)
  const int l31  = lane & 31;
  const int hi5  = lane >> 5;

  // XCD-chunked, heavy-first: Bx -> (bh, j), j=0..34 -> (q, chunk)
  const int Bx  = blockIdx.x;       // 1120
  const int xcd = Bx & 7, i_ = Bx >> 3;
  const int bh  = xcd * 4 + (i_ & 3);
  const int j   = i_ >> 2;
  int q, c;
  if (j < 18)      { q = 15 - j / 3;       c = j % 3; }
  else if (j < 32) { q = 9 - (j - 18) / 2; c = (j - 18) & 1; }
  else             { q = 34 - j;           c = 0; }
  const int b = bh >> 4, h = bh & 15;
  const int tot = 2 * q + 2, nc = nchunks(q);
  const int base = tot / nc, rem = tot - base * nc;
  const int R  = base + (c < rem ? 1 : 0);
  const int t0 = c * base + (c < rem ? c : rem);
  const int q0 = q << 7;
  const int qw = q0 + sub * 32;

  const float cs = 0.125f * 1.44269504088896f;  // 1/sqrt(E) * log2(e)

  // ---- Q fragments (B-operand of swapped QK^T), pre-scaled ----
  bf16x8 qf[4];
  {
    const int qg = qw + l31;
    const float* gq = Qp + ((size_t)(b * L_ + qg) * H_ + h) * E_ + hi5 * 8;
    #pragma unroll
    for (int ec = 0; ec < 4; ++ec) {
      float4 a = *(const float4*)(gq + ec * 16);
      float4 cc = *(const float4*)(gq + ec * 16 + 4);
      uint4 u;
      u.x = pkbf(a.x * cs, a.y * cs);
      u.y = pkbf(a.z * cs, a.w * cs);
      u.z = pkbf(cc.x * cs, cc.y * cs);
      u.w = pkbf(cc.z * cs, cc.w * cs);
      qf[ec] = *(bf16x8*)&u;
    }
  }

  f32x16 acc[2];
  #pragma unroll
  for (int dt = 0; dt < 2; ++dt)
    #pragma unroll
    for (int rr = 0; rr < 16; ++rr) acc[dt][rr] = 0.f;
  float mrun = -INFINITY, lsum = 0.f;

  const char* gK = ws + KOFF + ((size_t)bh * 32) * 8192;
  const char* gV = ws + VOFF + ((size_t)bh * 32) * 8192;

#define STAGE(buf_, t_) do {                                        \
    const char* sk = gK + (size_t)(t_) * 8192 + tid * 16;           \
    const char* sv = gV + (size_t)(t_) * 8192 + tid * 16;           \
    char* lb = (char*)&sbuf[(buf_)][0] + tid * 16;                  \
    GLL(sk, lb); GLL(sk + 4096, lb + 4096);                         \
    GLL(sv, lb + 8192); GLL(sv + 4096, lb + 12288);                 \
  } while (0)

  STAGE(0, t0);
  __syncthreads();

  int cur = 0;
  for (int t = t0; t < t0 + R; ++t, cur ^= 1) {
    if (t + 1 < t0 + R) STAGE(cur ^ 1, t + 1);   // uniform, all lanes active

    const int kv0 = t * 64;
    if (kv0 <= qw + 31) {
      char* lk = (char*)&sbuf[cur][0];
      char* lv = lk + 8192;
      const bool needmask = (kv0 + 63) > qw;

      // swapped QK^T: st[c2] = S^T[kv 32c2..][q]
      f32x16 st[2];
      #pragma unroll
      for (int c2 = 0; c2 < 2; ++c2)
        #pragma unroll
        for (int rr = 0; rr < 16; ++rr) st[c2][rr] = 0.f;
      __builtin_amdgcn_s_setprio(1);
      #pragma unroll
      for (int c2 = 0; c2 < 2; ++c2) {
        const int row = c2 * 32 + l31;
        const int sw = (row & 7) << 4;
        #pragma unroll
        for (int ec = 0; ec < 4; ++ec) {
          bf16x8 kf = *(bf16x8*)(lk + ((row * 128 + ec * 32 + hi5 * 16) ^ sw));
          st[c2] = __builtin_amdgcn_mfma_f32_32x32x16_bf16(kf, qf[ec], st[c2], 0, 0, 0);
        }
      }
      __builtin_amdgcn_s_setprio(0);

      if (needmask) {
        const int qg = qw + l31;
        #pragma unroll
        for (int c2 = 0; c2 < 2; ++c2)
          #pragma unroll
          for (int rr = 0; rr < 16; ++rr)
            if (kv0 + c2 * 32 + crow(rr, hi5) > qg) st[c2][rr] = -1e30f;
      }

      // online softmax, defer-max (THR=8 in log2 domain)
      float pm = st[0][0];
      #pragma unroll
      for (int c2 = 0; c2 < 2; ++c2)
        #pragma unroll
        for (int rr = 0; rr < 16; ++rr) pm = fmaxf(pm, st[c2][rr]);
      pm = fmaxf(pm, __shfl_xor(pm, 32));

      if (__any(pm > mrun + 8.f)) {
        const float mn = fmaxf(mrun, pm);
        const float f = EXP2(mrun - mn);
        mrun = mn;
        lsum *= f;
        #pragma unroll
        for (int rr = 0; rr < 16; ++rr) {
          const float fr = __shfl(f, crow(rr, hi5));
          acc[0][rr] *= fr;
          acc[1][rr] *= fr;
        }
      }
      {
        float ps = 0.f;
        #pragma unroll
        for (int c2 = 0; c2 < 2; ++c2)
          #pragma unroll
          for (int rr = 0; rr < 16; ++rr) {
            st[c2][rr] = EXP2(st[c2][rr] - mrun);
            ps += st[c2][rr];
          }
        ps += __shfl_xor(ps, 32);
        lsum += ps;
      }

      // P -> PA fragments (pack pairs + lane^32 exchange)
      uint4 pa[4];
      #pragma unroll
      for (int c2 = 0; c2 < 2; ++c2) {
        unsigned Dw[8];
        #pragma unroll
        for (int jj = 0; jj < 8; ++jj)
          Dw[jj] = pkbf(st[c2][2 * jj], st[c2][2 * jj + 1]);
        unsigned y0 = __shfl_xor((int)(hi5 ? Dw[0] : Dw[2]), 32);
        unsigned y1 = __shfl_xor((int)(hi5 ? Dw[1] : Dw[3]), 32);
        unsigned y2 = __shfl_xor((int)(hi5 ? Dw[4] : Dw[6]), 32);
        unsigned y3 = __shfl_xor((int)(hi5 ? Dw[5] : Dw[7]), 32);
        uint4 p0, p1;
        if (hi5) {
          p0 = uint4{y0, y1, Dw[2], Dw[3]};
          p1 = uint4{y2, y3, Dw[6], Dw[7]};
        } else {
          p0 = uint4{Dw[0], Dw[1], y0, y1};
          p1 = uint4{Dw[4], Dw[5], y2, y3};
        }
        pa[2 * c2]     = p0;
        pa[2 * c2 + 1] = p1;
      }

      // PV: acc[dt] += P(32q x 16kv) . V(16kv x 32d)
      __builtin_amdgcn_s_setprio(1);
      #pragma unroll
      for (int s = 0; s < 4; ++s) {
        #pragma unroll
        for (int dt = 0; dt < 2; ++dt) {
          const int row = dt * 32 + l31;
          bf16x8 vf = *(bf16x8*)(lv + ((row * 128 + s * 32 + hi5 * 16) ^ ((row & 7) << 4)));
          acc[dt] = __builtin_amdgcn_mfma_f32_32x32x16_bf16(*(bf16x8*)&pa[s], vf, acc[dt], 0, 0, 0);
        }
      }
      __builtin_amdgcn_s_setprio(0);
    }
    __syncthreads();
  }

  // ---- write bf16 partial + (m,l); merge kernel combines (no fences) ----
  char* slot = ws + POFF + ((size_t)(bh * 35 + slotoff(q, c))) * SLOT_BYTES;
  uint4* pw = (uint4*)(slot + (size_t)(sub * 64 + lane) * 64);
  #pragma unroll
  for (int dt = 0; dt < 2; ++dt) {
    uint4 A{pkbf(acc[dt][0], acc[dt][1]),  pkbf(acc[dt][2], acc[dt][3]),
            pkbf(acc[dt][4], acc[dt][5]),  pkbf(acc[dt][6], acc[dt][7])};
    uint4 Bq{pkbf(acc[dt][8], acc[dt][9]),  pkbf(acc[dt][10], acc[dt][11]),
             pkbf(acc[dt][12], acc[dt][13]), pkbf(acc[dt][14], acc[dt][15])};
    pw[dt * 2]     = A;
    pw[dt * 2 + 1] = Bq;
  }
  ((float2*)(slot + 16384))[sub * 64 + lane] = float2{mrun, lsum};
#undef STAGE
}

// ---------------- merge: LSE-combine 1..3 partials per (bh,q) -> O ----------
__device__ __forceinline__ void unpk(uint4 a, uint4 b, float* o) {
  const unsigned* pa = (const unsigned*)&a;
  const unsigned* pb = (const unsigned*)&b;
  #pragma unroll
  for (int i = 0; i < 4; ++i) {
    o[2 * i]     = bf2f(pa[i] & 0xffffu);
    o[2 * i + 1] = bf2f(pa[i] >> 16);
    o[8 + 2 * i]     = bf2f(pb[i] & 0xffffu);
    o[8 + 2 * i + 1] = bf2f(pb[i] >> 16);
  }
}

__global__ __launch_bounds__(256)
void fa_merge(float* __restrict__ Op, const char* __restrict__ ws) {
  const int Bx = blockIdx.x;        // 512 = 32 bh x 16 q
  const int bh = Bx >> 4, q = Bx & 15;
  const int b = bh >> 4, h = bh & 15;
  const int tid = threadIdx.x, lane = tid & 63, sub = tid >> 6;
  const int l31 = lane & 31, hi5 = lane >> 5;
  const int nc = nchunks(q);
  const char* sbase = ws + POFF;

  float A0[16], A1[16], M, Lw;
  {
    const char* s0 = sbase + ((size_t)(bh * 35 + slotoff(q, 0))) * SLOT_BYTES;
    const uint4* pr = (const uint4*)(s0 + (size_t)(sub * 64 + lane) * 64);
    unpk(pr[0], pr[1], A0);
    unpk(pr[2], pr[3], A1);
    float2 ml = ((const float2*)(s0 + 16384))[sub * 64 + lane];
    M = ml.x; Lw = ml.y;
  }
  for (int ci = 1; ci < nc; ++ci) {
    const char* si = sbase + ((size_t)(bh * 35 + slotoff(q, ci))) * SLOT_BYTES;
    const uint4* pr = (const uint4*)(si + (size_t)(sub * 64 + lane) * 64);
    float a0[16], a1[16];
    unpk(pr[0], pr[1], a0);
    unpk(pr[2], pr[3], a1);
    float2 ml = ((const float2*)(si + 16384))[sub * 64 + lane];
    const float mm = fmaxf(M, ml.x);
    const float fA = EXP2(M - mm);
    const float fI = EXP2(ml.x - mm);    // exp2(-inf)=0 covers empty partial
    Lw = Lw * fA + ml.y * fI;
    M = mm;
    #pragma unroll
    for (int rr = 0; rr < 16; ++rr) {
      const int cr = crow(rr, hi5);
      const float fAb = __shfl(fA, cr);
      const float fIb = __shfl(fI, cr);
      A0[rr] = A0[rr] * fAb + a0[rr] * fIb;
      A1[rr] = A1[rr] * fAb + a1[rr] * fIb;
    }
  }
  const float inv = 1.f / Lw;
  #pragma unroll
  for (int rr = 0; rr < 16; ++rr) {
    const int cr = crow(rr, hi5);
    const float wv = __shfl(inv, cr);
    const int qg = (q << 7) + sub * 32 + cr;
    float* go = Op + ((size_t)(b * L_ + qg) * H_ + h) * D_ + l31;
    go[0]  = A0[rr] * wv;
    go[32] = A1[rr] * wv;
  }
}

extern "C" void kernel_launch(void* const* d_in, const int* in_sizes, int n_in,
                              void* d_out, int out_size, void* d_ws, size_t ws_size,
                              hipStream_t stream) {
  (void)in_sizes; (void)n_in; (void)out_size; (void)ws_size;
  const float* Q = (const float*)d_in[0];
  const float* K = (const float*)d_in[1];
  const float* V = (const float*)d_in[2];
  float* O = (float*)d_out;
  char* ws = (char*)d_ws;   // ws_size >= 37.75MB proven (r10); WS_NEED = 37.42MB
  fa_pre<<<dim3(1024), dim3(256), 0, stream>>>(K, V, ws);
  fa_main<<<dim3(1120), dim3(256), 0, stream>>>(Q, ws);
  fa_merge<<<dim3(512), dim3(256), 0, stream>>>(O, ws);
}